// Round 4
// baseline (246.169 us; speedup 1.0000x reference)
//
#include <hip/hip_runtime.h>
#include <math.h>

// VQ-VAE forward. inputs [16,256,64,64] f32 NCHW, codebook [1024,256] f32.
// N = 65536 points, D = 256, K = 1024.
// d_out f32: z_out [16,256,64,64] | loss | perplexity | idx [65536,1]
#define NPTS   65536
#define DDIM   256
#define KCODES 1024
#define HWSZ   4096
#define ZELEMS 16777216
#define CHW    1048576

// bf16-split GEMM, contraction C=1024 = [xhi|xhi|xlo|xlo].[whi|wlo|whi|wlo].
// 8-phase 256x256 schedule (T3+T4+T5), fragment-ordered global tiles.
// X layout: [mt 256][chunk 16][rhalf 2][ms 8][lane 64][8] bf16 (64 MiB, z_out scratch)
//   chunk: 0-7 = hi(d=c*32..), 8-15 = lo. lane = (row&15)+16*k_octet.
// W layout: [ct 4][chunk 16][chalf 2][ms 8][lane 64][8] bf16 (1 MiB, ws)
// ws: counts u32[1K] @0 | ww f32[1K] @4096 | partials @8192 | Ws @16384 | pbest u64[4][64K] @1064960

typedef __attribute__((ext_vector_type(8))) short s16x8;
typedef __attribute__((ext_vector_type(4))) float f32x4;

__device__ __forceinline__ void bf16split(float x, unsigned short& h, unsigned short& l) {
    unsigned u  = __float_as_uint(x);
    unsigned hu = (u + 0x8000u) & 0xFFFF0000u;
    h = (unsigned short)(hu >> 16);
    float r = x - __uint_as_float(hu);
    l = (unsigned short)((__float_as_uint(r) + 0x8000u) >> 16);
}

// ------------------------------------------- conv_w: codebook -> tiles + ||w||^2
__global__ __launch_bounds__(256) void conv_w(const float* __restrict__ cb,
                                              unsigned short* __restrict__ Ws,
                                              float* __restrict__ ww) {
    int gid  = blockIdx.x * 256 + threadIdx.x;           // 0..8191
    int code = gid >> 3, o32 = gid & 7;
    int ct = code >> 8, r256 = code & 255, rh = r256 >> 7, rr = r256 & 127;
    unsigned short hi[32], lo[32];
    float ss = 0.f;
#pragma unroll
    for (int j4 = 0; j4 < 8; ++j4) {
        float4 v = *(const float4*)(cb + (size_t)code * DDIM + o32 * 32 + j4 * 4);
        ss += v.x * v.x + v.y * v.y + v.z * v.z + v.w * v.w;
        bf16split(v.x, hi[j4*4+0], lo[j4*4+0]);
        bf16split(v.y, hi[j4*4+1], lo[j4*4+1]);
        bf16split(v.z, hi[j4*4+2], lo[j4*4+2]);
        bf16split(v.w, hi[j4*4+3], lo[j4*4+3]);
    }
    ss += __shfl_down(ss, 4, 8);
    ss += __shfl_down(ss, 2, 8);
    ss += __shfl_down(ss, 1, 8);
    if (o32 == 0) ww[code] = ss;
    size_t bh = (size_t)ct * 131072 + (size_t)o32       * 8192 + rh * 4096 + (rr >> 4) * 512;
    size_t bl = (size_t)ct * 131072 + (size_t)(o32 + 8) * 8192 + rh * 4096 + (rr >> 4) * 512;
#pragma unroll
    for (int oct = 0; oct < 4; ++oct) {
        size_t fo = (size_t)((rr & 15) + 16 * oct) * 8;
        *(s16x8*)(Ws + bh + fo) = *(const s16x8*)&hi[oct * 8];
        *(s16x8*)(Ws + bl + fo) = *(const s16x8*)&lo[oct * 8];
    }
}

// --------------------------------- conv_x: NCHW f32 -> fragment-ordered bf16
__global__ __launch_bounds__(256) void conv_x(const float* __restrict__ in,
                                              unsigned short* __restrict__ Xs) {
    __shared__ float xt[32 * 128];                       // 16 KB
    const int tid = threadIdx.x;
    const int rg = blockIdx.x >> 3, dc = blockIdx.x & 7; // rowgroup, d-chunk
    const int mt = rg >> 1, rhalf = rg & 1;
    const int b = (rg * 128) >> 12, hw0 = (rg * 128) & 4095;
    const float* src = in + (size_t)b * CHW + (size_t)(dc * 32) * HWSZ + hw0;
#pragma unroll
    for (int r = 0; r < 16; ++r) {
        int e = r * 256 + tid, dd = e >> 7, i = e & 127;
        xt[dd * 128 + i] = src[(size_t)dd * HWSZ + i];
    }
    __syncthreads();
#pragma unroll
    for (int hl = 0; hl < 2; ++hl) {
        int g = hl * 256 + tid;                          // 0..511
        int row = g >> 2, o = g & 3;                     // row 0..127, k-octet
        unsigned short hi[8], lo[8];
#pragma unroll
        for (int j = 0; j < 8; ++j)
            bf16split(xt[(o * 8 + j) * 128 + row], hi[j], lo[j]);
        size_t fo = rhalf * 4096 + (size_t)(row >> 4) * 512 + (size_t)((row & 15) + 16 * o) * 8;
        size_t bh = (size_t)mt * 131072 + (size_t)dc       * 8192 + fo;
        size_t bl = (size_t)mt * 131072 + (size_t)(dc + 8) * 8192 + fo;
        *(s16x8*)(Xs + bh) = *(const s16x8*)hi;
        *(s16x8*)(Xs + bl) = *(const s16x8*)lo;
    }
}

// --------------------------------------- gemm_argmin: 8-phase MFMA + argmin
// 1024 blocks (256 mb x 4 nt) x 512 threads (8 waves, 2M x 4N; wave tile 128x64).
__global__ __launch_bounds__(512, 2) void gemm_argmin(
        const unsigned short* __restrict__ Xs, const unsigned short* __restrict__ Ws,
        const float* __restrict__ ww, unsigned long long* __restrict__ pbest) {
    __shared__ unsigned short lds[65536];                // 128 KB: [buf][A/B][kc][h][ms][lane][8]
    const int tid = threadIdx.x, lane = tid & 63, w = tid >> 6;
    const int wm = w >> 2, wn = w & 3;
    const int col = lane & 15, q = lane >> 4;
    const int mb = blockIdx.x & 255, nt = blockIdx.x >> 8;

    const unsigned short* XsB = Xs + (size_t)mb * 131072;
    const unsigned short* WsB = Ws + (size_t)nt * 131072;

    f32x4 acc[8][4] = {};

    // stage one 8KB chunk-half: 1 instr/thread, lane-linear, wave-uniform LDS base
    auto SA = [&](int tt, int kc, int h) {
        if (tt > 15) return;
        int a = ((tt >> 3) & 1) * 8 + (tt & 3) * 2 + kc;
        const unsigned short* src = XsB + a * 8192 + h * 4096 + tid * 8;
        int dst = (tt & 1) * 32768 + (kc * 2 + h) * 4096 + w * 512;
        __builtin_amdgcn_global_load_lds(
            (const __attribute__((address_space(1))) unsigned*)src,
            (__attribute__((address_space(3))) unsigned*)&lds[dst], 16, 0, 0);
    };
    auto SB = [&](int tt, int kc, int h) {
        if (tt > 15) return;
        int b = ((tt >> 2) & 1) * 8 + (tt & 3) * 2 + kc;
        const unsigned short* src = WsB + b * 8192 + h * 4096 + tid * 8;
        int dst = (tt & 1) * 32768 + 16384 + (kc * 2 + h) * 4096 + w * 512;
        __builtin_amdgcn_global_load_lds(
            (const __attribute__((address_space(1))) unsigned*)src,
            (__attribute__((address_space(3))) unsigned*)&lds[dst], 16, 0, 0);
    };

    // prologue: t0 B(4), t0 A(4), t1 B(4); gate leaves t1's B in flight
    SB(0,0,0); SB(0,0,1); SB(0,1,0); SB(0,1,1);
    SA(0,0,0); SA(0,0,1); SA(0,1,0); SA(0,1,1);
    SB(1,0,0); SB(1,0,1); SB(1,1,0); SB(1,1,1);
    asm volatile("s_waitcnt vmcnt(4)" ::: "memory");
    __builtin_amdgcn_s_barrier();

    for (int t = 0; t < 16; ++t) {
        const int bb = (t & 1) * 32768;
        s16x8 b0[4], b1[4];
        // ---- P0: read A(m-half0)+B(n-half0); stage t+1 A kc0
        s16x8 a0[8];
#pragma unroll
        for (int mf = 0; mf < 4; ++mf)
#pragma unroll
            for (int kc = 0; kc < 2; ++kc)
                a0[mf*2+kc] = *(const s16x8*)&lds[bb + ((kc*2+wm)*8 + mf)*512 + lane*8];
#pragma unroll
        for (int nf = 0; nf < 2; ++nf)
#pragma unroll
            for (int kc = 0; kc < 2; ++kc)
                b0[nf*2+kc] = *(const s16x8*)&lds[bb + 16384 + ((kc*2+(wn>>1))*8 + (wn&1)*4 + nf)*512 + lane*8];
        SA(t+1, 0, 0); SA(t+1, 0, 1);
        __builtin_amdgcn_s_barrier();
        __builtin_amdgcn_s_setprio(1);
#pragma unroll
        for (int mf = 0; mf < 4; ++mf)
#pragma unroll
            for (int nf = 0; nf < 2; ++nf) {
                acc[mf][nf] = __builtin_amdgcn_mfma_f32_16x16x32_bf16(a0[mf*2],   b0[nf*2],   acc[mf][nf], 0,0,0);
                acc[mf][nf] = __builtin_amdgcn_mfma_f32_16x16x32_bf16(a0[mf*2+1], b0[nf*2+1], acc[mf][nf], 0,0,0);
            }
        __builtin_amdgcn_s_setprio(0);
        __builtin_amdgcn_s_barrier();
        // ---- P1: read B(n-half1); stage t+1 A kc1
#pragma unroll
        for (int nf = 0; nf < 2; ++nf)
#pragma unroll
            for (int kc = 0; kc < 2; ++kc)
                b1[nf*2+kc] = *(const s16x8*)&lds[bb + 16384 + ((kc*2+(wn>>1))*8 + (wn&1)*4 + 2 + nf)*512 + lane*8];
        SA(t+1, 1, 0); SA(t+1, 1, 1);
        __builtin_amdgcn_s_barrier();
        __builtin_amdgcn_s_setprio(1);
#pragma unroll
        for (int mf = 0; mf < 4; ++mf)
#pragma unroll
            for (int nf = 0; nf < 2; ++nf) {
                acc[mf][nf+2] = __builtin_amdgcn_mfma_f32_16x16x32_bf16(a0[mf*2],   b1[nf*2],   acc[mf][nf+2], 0,0,0);
                acc[mf][nf+2] = __builtin_amdgcn_mfma_f32_16x16x32_bf16(a0[mf*2+1], b1[nf*2+1], acc[mf][nf+2], 0,0,0);
            }
        __builtin_amdgcn_s_setprio(0);
        __builtin_amdgcn_s_barrier();
        // ---- P2: read A(m-half1); stage t+2 B kc0 (regions dead since P1 barrier)
        s16x8 a1[8];
#pragma unroll
        for (int mf = 0; mf < 4; ++mf)
#pragma unroll
            for (int kc = 0; kc < 2; ++kc)
                a1[mf*2+kc] = *(const s16x8*)&lds[bb + ((kc*2+wm)*8 + 4 + mf)*512 + lane*8];
        SB(t+2, 0, 0); SB(t+2, 0, 1);
        __builtin_amdgcn_s_barrier();
        __builtin_amdgcn_s_setprio(1);
#pragma unroll
        for (int mf = 0; mf < 4; ++mf)
#pragma unroll
            for (int nf = 0; nf < 2; ++nf) {
                acc[mf+4][nf] = __builtin_amdgcn_mfma_f32_16x16x32_bf16(a1[mf*2],   b0[nf*2],   acc[mf+4][nf], 0,0,0);
                acc[mf+4][nf] = __builtin_amdgcn_mfma_f32_16x16x32_bf16(a1[mf*2+1], b0[nf*2+1], acc[mf+4][nf], 0,0,0);
            }
        __builtin_amdgcn_s_setprio(0);
        __builtin_amdgcn_s_barrier();
        // ---- P3: no reads; stage t+2 B kc1; gate before trailing barrier
        SB(t+2, 1, 0); SB(t+2, 1, 1);
        __builtin_amdgcn_s_barrier();
        __builtin_amdgcn_s_setprio(1);
#pragma unroll
        for (int mf = 0; mf < 4; ++mf)
#pragma unroll
            for (int nf = 0; nf < 2; ++nf) {
                acc[mf+4][nf+2] = __builtin_amdgcn_mfma_f32_16x16x32_bf16(a1[mf*2],   b1[nf*2],   acc[mf+4][nf+2], 0,0,0);
                acc[mf+4][nf+2] = __builtin_amdgcn_mfma_f32_16x16x32_bf16(a1[mf*2+1], b1[nf*2+1], acc[mf+4][nf+2], 0,0,0);
            }
        __builtin_amdgcn_s_setprio(0);
        if (t == 14)      asm volatile("s_waitcnt vmcnt(0)" ::: "memory");
        else if (t < 14)  asm volatile("s_waitcnt vmcnt(4)" ::: "memory");
        __builtin_amdgcn_s_barrier();
    }

    // ---- epilogue: per-row argmin -> packed u64 (monotonic dist, global k)
    __syncthreads();
    unsigned long long* kbuf = (unsigned long long*)lds;  // [256][4]
    float wv[4];
#pragma unroll
    for (int nf = 0; nf < 4; ++nf) wv[nf] = ww[nt * 256 + wn * 64 + nf * 16 + col];
#pragma unroll
    for (int mf = 0; mf < 8; ++mf)
#pragma unroll
        for (int r = 0; r < 4; ++r) {
            unsigned long long key = ~0ull;
#pragma unroll
            for (int nf = 0; nf < 4; ++nf) {
                int kg = nt * 256 + wn * 64 + nf * 16 + col;
                float sd = wv[nf] - 2.f * acc[mf][nf][r];
                unsigned u = __float_as_uint(sd);
                u = (u & 0x80000000u) ? ~u : (u | 0x80000000u);
                unsigned long long kk = ((unsigned long long)u << 32) | (unsigned)kg;
                key = kk < key ? kk : key;
            }
#pragma unroll
            for (int off = 1; off < 16; off <<= 1) {
                unsigned klo = __shfl_xor((unsigned)key, off, 64);
                unsigned khi = __shfl_xor((unsigned)(key >> 32), off, 64);
                unsigned long long ok = ((unsigned long long)khi << 32) | klo;
                key = ok < key ? ok : key;
            }
            if (col == 0) kbuf[(wm * 128 + mf * 16 + q * 4 + r) * 4 + wn] = key;
        }
    __syncthreads();
    if (tid < 256) {
        unsigned long long k0 = kbuf[tid * 4], k1 = kbuf[tid * 4 + 1];
        unsigned long long k2 = kbuf[tid * 4 + 2], k3 = kbuf[tid * 4 + 3];
        unsigned long long km = k0 < k1 ? k0 : k1;
        km = k2 < km ? k2 : km;
        km = k3 < km ? k3 : km;
        pbest[(size_t)nt * 65536 + mb * 256 + tid] = km;
    }
}

// -------------------------------------------- cross-block argmin + histogram
__global__ __launch_bounds__(256) void reduce_argmin(
        const unsigned long long* __restrict__ pbest, float* __restrict__ idx_out,
        unsigned int* __restrict__ counts) {
    int row = blockIdx.x * 256 + threadIdx.x;
    unsigned long long km = pbest[row];
#pragma unroll
    for (int nt = 1; nt < 4; ++nt) {
        unsigned long long k = pbest[(size_t)nt * 65536 + row];
        km = k < km ? k : km;
    }
    int kg = (int)(km & 0xFFFFFFFFu);
    idx_out[row] = (float)kg;
    atomicAdd(&counts[kg], 1u);
}

// ----------------------------------------------- gather + z_out + loss
__global__ __launch_bounds__(256) void gather_kernel(
        const float* __restrict__ in, const float* __restrict__ cb,
        const float* __restrict__ idx_f, float* __restrict__ zout,
        float* __restrict__ partials) {
    const int tid = threadIdx.x;
    const int n   = blockIdx.x * 256 + tid;
    const int b   = n >> 12, hw = n & 4095;
    const int r   = (int)idx_f[n];
    const float* row = cb + (size_t)r * DDIM;
    const float* xp  = in   + (size_t)b * CHW + hw;
    float*       zp  = zout + (size_t)b * CHW + hw;
    float sum = 0.f;
#pragma unroll 4
    for (int c = 0; c < DDIM; ++c) {
        float v = row[c];
        float x = xp[(size_t)c * HWSZ];
        zp[(size_t)c * HWSZ] = v;
        float d = v - x;
        sum += d * d;
    }
#pragma unroll
    for (int o = 32; o; o >>= 1) sum += __shfl_down(sum, o, 64);
    __shared__ float ps[4];
    if ((tid & 63) == 0) ps[tid >> 6] = sum;
    __syncthreads();
    if (tid == 0) partials[blockIdx.x] = ps[0] + ps[1] + ps[2] + ps[3];
}

// ------------------------------------------------------- loss + perplexity
__global__ __launch_bounds__(256) void final_kernel(
        const float* __restrict__ partials, const unsigned int* __restrict__ counts,
        float* __restrict__ out_loss, float* __restrict__ out_perp) {
    const int tid = threadIdx.x;
    float s = partials[tid];
    float e = 0.f;
#pragma unroll
    for (int qq = 0; qq < 4; ++qq) {
        float p = (float)counts[tid * 4 + qq] * (1.f / 65536.f);
        e += p * logf(p + 1e-10f);
    }
#pragma unroll
    for (int o = 32; o; o >>= 1) {
        s += __shfl_down(s, o, 64);
        e += __shfl_down(e, o, 64);
    }
    __shared__ float ss[4], es[4];
    if ((tid & 63) == 0) { ss[tid >> 6] = s; es[tid >> 6] = e; }
    __syncthreads();
    if (tid == 0) {
        float S = ss[0] + ss[1] + ss[2] + ss[3];
        float E = es[0] + es[1] + es[2] + es[3];
        *out_loss = 0.25f * (S / (float)ZELEMS);
        *out_perp = expf(-E);
    }
}

extern "C" void kernel_launch(void* const* d_in, const int* in_sizes, int n_in,
                              void* d_out, int out_size, void* d_ws, size_t ws_size,
                              hipStream_t stream) {
    (void)in_sizes; (void)n_in; (void)out_size; (void)ws_size;
    const float* in = (const float*)d_in[0];
    const float* cb = (const float*)d_in[1];
    float* out  = (float*)d_out;
    float* zout = out;
    float* loss = out + ZELEMS;
    float* perp = out + ZELEMS + 1;
    float* idxf = out + ZELEMS + 2;

    unsigned int*       counts   = (unsigned int*)d_ws;
    float*              ww       = (float*)((char*)d_ws + 4096);
    float*              partials = (float*)((char*)d_ws + 8192);
    unsigned short*     Ws       = (unsigned short*)((char*)d_ws + 16384);
    unsigned long long* pbest    = (unsigned long long*)((char*)d_ws + 1064960);
    unsigned short*     Xs       = (unsigned short*)zout;  // scratch; overwritten later

    hipMemsetAsync(counts, 0, 4096, stream);
    conv_w      <<<32,   256, 0, stream>>>(cb, Ws, ww);
    conv_x      <<<4096, 256, 0, stream>>>(in, Xs);
    gemm_argmin <<<1024, 512, 0, stream>>>(Xs, Ws, ww, pbest);
    reduce_argmin<<<256, 256, 0, stream>>>(pbest, idxf, counts);
    gather_kernel<<<256, 256, 0, stream>>>(in, cb, idxf, zout, partials);
    final_kernel <<<1,   256, 0, stream>>>(partials, counts, loss, perp);
}

// Round 5
// 238.829 us; speedup vs baseline: 1.0307x; 1.0307x over previous
//
#include <hip/hip_runtime.h>
#include <math.h>

// VQ-VAE forward. inputs [16,256,64,64] f32 NCHW, codebook [1024,256] f32.
// N = 65536 points, D = 256, K = 1024.
// d_out f32: z_out [16,256,64,64] | loss | perplexity | idx [65536,1]
#define NPTS   65536
#define DDIM   256
#define KCODES 1024
#define HWSZ   4096
#define ZELEMS 16777216
#define CHW    1048576

// bf16-split GEMM, contraction 1024 = [xhi|xhi|xlo|xlo].[whi|wlo|whi|wlo].
// Fragment-ordered tiles; BK=32 pipeline, 4 LDS buffers, prefetch distance 3.
// X layout: [mt 256][chunk 16][rhalf 2][ms 8][lane 64][8] bf16 (64 MiB, z_out scratch)
// W layout: [ct 4][chunk 16][chalf 2][ms 8][lane 64][8] bf16 (1 MiB, ws)
// ws: counts u32[1K] @0 | ww f32[1K] @4096 | partials @8192 | Ws @16384 | pbest u64[4][64K] @1064960

typedef __attribute__((ext_vector_type(8))) short s16x8;
typedef __attribute__((ext_vector_type(4))) float f32x4;

__device__ __forceinline__ void bf16split(float x, unsigned short& h, unsigned short& l) {
    unsigned u  = __float_as_uint(x);
    unsigned hu = (u + 0x8000u) & 0xFFFF0000u;
    h = (unsigned short)(hu >> 16);
    float r = x - __uint_as_float(hu);
    l = (unsigned short)((__float_as_uint(r) + 0x8000u) >> 16);
}

// ------------------------------------------- conv_w: codebook -> tiles + ||w||^2
__global__ __launch_bounds__(256) void conv_w(const float* __restrict__ cb,
                                              unsigned short* __restrict__ Ws,
                                              float* __restrict__ ww) {
    int gid  = blockIdx.x * 256 + threadIdx.x;           // 0..8191
    int code = gid >> 3, o32 = gid & 7;
    int ct = code >> 8, r256 = code & 255, rh = r256 >> 7, rr = r256 & 127;
    unsigned short hi[32], lo[32];
    float ss = 0.f;
#pragma unroll
    for (int j4 = 0; j4 < 8; ++j4) {
        float4 v = *(const float4*)(cb + (size_t)code * DDIM + o32 * 32 + j4 * 4);
        ss += v.x * v.x + v.y * v.y + v.z * v.z + v.w * v.w;
        bf16split(v.x, hi[j4*4+0], lo[j4*4+0]);
        bf16split(v.y, hi[j4*4+1], lo[j4*4+1]);
        bf16split(v.z, hi[j4*4+2], lo[j4*4+2]);
        bf16split(v.w, hi[j4*4+3], lo[j4*4+3]);
    }
    ss += __shfl_down(ss, 4, 8);
    ss += __shfl_down(ss, 2, 8);
    ss += __shfl_down(ss, 1, 8);
    if (o32 == 0) ww[code] = ss;
    size_t bh = (size_t)ct * 131072 + (size_t)o32       * 8192 + rh * 4096 + (rr >> 4) * 512;
    size_t bl = (size_t)ct * 131072 + (size_t)(o32 + 8) * 8192 + rh * 4096 + (rr >> 4) * 512;
#pragma unroll
    for (int oct = 0; oct < 4; ++oct) {
        size_t fo = (size_t)((rr & 15) + 16 * oct) * 8;
        *(s16x8*)(Ws + bh + fo) = *(const s16x8*)&hi[oct * 8];
        *(s16x8*)(Ws + bl + fo) = *(const s16x8*)&lo[oct * 8];
    }
}

// --------------------------------- conv_x: NCHW f32 -> fragment-ordered bf16
__global__ __launch_bounds__(256) void conv_x(const float* __restrict__ in,
                                              unsigned short* __restrict__ Xs) {
    __shared__ float xt[32 * 128];                       // 16 KB
    const int tid = threadIdx.x;
    const int rg = blockIdx.x >> 3, dc = blockIdx.x & 7;
    const int mt = rg >> 1, rhalf = rg & 1;
    const int b = (rg * 128) >> 12, hw0 = (rg * 128) & 4095;
    const float* src = in + (size_t)b * CHW + (size_t)(dc * 32) * HWSZ + hw0;
#pragma unroll
    for (int r = 0; r < 16; ++r) {
        int e = r * 256 + tid, dd = e >> 7, i = e & 127;
        xt[dd * 128 + i] = src[(size_t)dd * HWSZ + i];
    }
    __syncthreads();
#pragma unroll
    for (int hl = 0; hl < 2; ++hl) {
        int g = hl * 256 + tid;
        int row = g >> 2, o = g & 3;
        unsigned short hi[8], lo[8];
#pragma unroll
        for (int j = 0; j < 8; ++j)
            bf16split(xt[(o * 8 + j) * 128 + row], hi[j], lo[j]);
        size_t fo = rhalf * 4096 + (size_t)(row >> 4) * 512 + (size_t)((row & 15) + 16 * o) * 8;
        size_t bh = (size_t)mt * 131072 + (size_t)dc       * 8192 + fo;
        size_t bl = (size_t)mt * 131072 + (size_t)(dc + 8) * 8192 + fo;
        *(s16x8*)(Xs + bh) = *(const s16x8*)hi;
        *(s16x8*)(Xs + bl) = *(const s16x8*)lo;
    }
}

// --------------------------------------- gemm_argmin: pipelined MFMA + argmin
// 1024 blocks x 512 threads (8 waves 2Mx4N; wave tile 128x64). BK=32.
// XCD swizzle: 4 nt-blocks of one mb run concurrently on one XCD (share X in L2).
__global__ __launch_bounds__(512) void gemm_argmin(
        const unsigned short* __restrict__ Xs, const unsigned short* __restrict__ Ws,
        const float* __restrict__ ww, unsigned long long* __restrict__ pbest) {
    __shared__ unsigned short lds[65536];                // 128 KB = 4 bufs x 32 KB
    const int tid = threadIdx.x, lane = tid & 63, w = tid >> 6;
    const int wm = w >> 2, wn = w & 3;
    const int col = lane & 15, q = lane >> 4;
    const int bid = blockIdx.x;
    const int xcd = bid & 7, slot = bid >> 3;
    const int nt = slot & 3, mb = (slot >> 2) * 8 + xcd;

    const unsigned short* XsB = Xs + (size_t)mb * 131072;
    const unsigned short* WsB = Ws + (size_t)nt * 131072;

    f32x4 acc[8][4] = {};

    // stage one 8 KB granule (1 instr/wave, lane-linear, wave-uniform LDS base)
    auto SA = [&](int g, int h) {
        const int kA = (g & 7) | ((g >> 4) << 3);        // hi,hi,lo,lo
        const unsigned short* src = XsB + kA * 8192 + h * 4096 + tid * 8;
        const int dst = (g & 3) * 16384 + h * 4096 + w * 512;
        __builtin_amdgcn_global_load_lds(
            (const __attribute__((address_space(1))) unsigned*)src,
            (__attribute__((address_space(3))) unsigned*)&lds[dst], 16, 0, 0);
    };
    auto SB = [&](int g, int h) {
        const int kW = (g & 7) | (((g >> 3) & 1) << 3);  // hi,lo,hi,lo
        const unsigned short* src = WsB + kW * 8192 + h * 4096 + tid * 8;
        const int dst = (g & 3) * 16384 + 8192 + h * 4096 + w * 512;
        __builtin_amdgcn_global_load_lds(
            (const __attribute__((address_space(1))) unsigned*)src,
            (__attribute__((address_space(3))) unsigned*)&lds[dst], 16, 0, 0);
    };

    // tile body: 2 phases; stage tile g+3; gate: 8/4/0, -1 = none
    auto tile = [&](int g, bool stg, int gate) {
        const int bb = (g & 3) * 16384;
        s16x8 a[8], b01[2], b23[2];
#pragma unroll
        for (int mf = 0; mf < 8; ++mf)
            a[mf] = *(const s16x8*)&lds[bb + wm * 4096 + mf * 512 + lane * 8];
#pragma unroll
        for (int nf = 0; nf < 2; ++nf)
            b01[nf] = *(const s16x8*)&lds[bb + 8192 + (wn >> 1) * 4096 + ((wn & 1) * 4 + nf) * 512 + lane * 8];
        if (stg) { SA(g + 3, 0); SA(g + 3, 1); }
        __builtin_amdgcn_s_barrier();
        __builtin_amdgcn_s_setprio(1);
#pragma unroll
        for (int mf = 0; mf < 8; ++mf) {
            acc[mf][0] = __builtin_amdgcn_mfma_f32_16x16x32_bf16(a[mf], b01[0], acc[mf][0], 0, 0, 0);
            acc[mf][1] = __builtin_amdgcn_mfma_f32_16x16x32_bf16(a[mf], b01[1], acc[mf][1], 0, 0, 0);
        }
        __builtin_amdgcn_s_setprio(0);
        __builtin_amdgcn_s_barrier();
#pragma unroll
        for (int nf = 0; nf < 2; ++nf)
            b23[nf] = *(const s16x8*)&lds[bb + 8192 + (wn >> 1) * 4096 + ((wn & 1) * 4 + 2 + nf) * 512 + lane * 8];
        if (stg) { SB(g + 3, 0); SB(g + 3, 1); }
        __builtin_amdgcn_s_barrier();
        __builtin_amdgcn_s_setprio(1);
#pragma unroll
        for (int mf = 0; mf < 8; ++mf) {
            acc[mf][2] = __builtin_amdgcn_mfma_f32_16x16x32_bf16(a[mf], b23[0], acc[mf][2], 0, 0, 0);
            acc[mf][3] = __builtin_amdgcn_mfma_f32_16x16x32_bf16(a[mf], b23[1], acc[mf][3], 0, 0, 0);
        }
        __builtin_amdgcn_s_setprio(0);
        if (gate == 8)      asm volatile("s_waitcnt vmcnt(8)" ::: "memory");
        else if (gate == 4) asm volatile("s_waitcnt vmcnt(4)" ::: "memory");
        else if (gate == 0) asm volatile("s_waitcnt vmcnt(0)" ::: "memory");
        __builtin_amdgcn_s_barrier();
    };

    // prologue: stage tiles 0,1,2 (12 granules); gate so tile 0 is resident
    for (int g = 0; g < 3; ++g) { SA(g, 0); SA(g, 1); SB(g, 0); SB(g, 1); }
    asm volatile("s_waitcnt vmcnt(8)" ::: "memory");
    __builtin_amdgcn_s_barrier();

    for (int g = 0; g < 29; ++g) tile(g, true, 8);
    tile(29, false, 4);
    tile(30, false, 0);
    tile(31, false, -1);

    // ---- epilogue: per-row argmin -> packed u64 (monotonic dist, global k)
    __syncthreads();
    unsigned long long* kbuf = (unsigned long long*)lds;  // [256][4]
    float wv[4];
#pragma unroll
    for (int nf = 0; nf < 4; ++nf) wv[nf] = ww[nt * 256 + wn * 64 + nf * 16 + col];
#pragma unroll
    for (int mf = 0; mf < 8; ++mf)
#pragma unroll
        for (int r = 0; r < 4; ++r) {
            unsigned long long key = ~0ull;
#pragma unroll
            for (int nf = 0; nf < 4; ++nf) {
                int kg = nt * 256 + wn * 64 + nf * 16 + col;
                float sd = wv[nf] - 2.f * acc[mf][nf][r];
                unsigned u = __float_as_uint(sd);
                u = (u & 0x80000000u) ? ~u : (u | 0x80000000u);
                unsigned long long kk = ((unsigned long long)u << 32) | (unsigned)kg;
                key = kk < key ? kk : key;
            }
#pragma unroll
            for (int off = 1; off < 16; off <<= 1) {
                unsigned klo = __shfl_xor((unsigned)key, off, 64);
                unsigned khi = __shfl_xor((unsigned)(key >> 32), off, 64);
                unsigned long long ok = ((unsigned long long)khi << 32) | klo;
                key = ok < key ? ok : key;
            }
            if (col == 0) kbuf[(wm * 128 + mf * 16 + q * 4 + r) * 4 + wn] = key;
        }
    __syncthreads();
    if (tid < 256) {
        unsigned long long k0 = kbuf[tid * 4], k1 = kbuf[tid * 4 + 1];
        unsigned long long k2 = kbuf[tid * 4 + 2], k3 = kbuf[tid * 4 + 3];
        unsigned long long km = k0 < k1 ? k0 : k1;
        km = k2 < km ? k2 : km;
        km = k3 < km ? k3 : km;
        pbest[(size_t)nt * 65536 + mb * 256 + tid] = km;
    }
}

// --------------------- gather: cross-block argmin + idx + z_out + loss + counts
__global__ __launch_bounds__(256) void gather_kernel(
        const float* __restrict__ in, const float* __restrict__ cb,
        const unsigned long long* __restrict__ pbest, float* __restrict__ idx_out,
        unsigned int* __restrict__ counts, float* __restrict__ zout,
        float* __restrict__ partials) {
    const int tid = threadIdx.x;
    const int n   = blockIdx.x * 256 + tid;
    unsigned long long km = pbest[n];
#pragma unroll
    for (int nt = 1; nt < 4; ++nt) {
        unsigned long long k = pbest[(size_t)nt * 65536 + n];
        km = k < km ? k : km;
    }
    const int r = (int)(km & 0xFFFFFFFFu);
    idx_out[n] = (float)r;
    atomicAdd(&counts[r], 1u);

    const int b = n >> 12, hw = n & 4095;
    const float* row = cb + (size_t)r * DDIM;
    const float* xp  = in   + (size_t)b * CHW + hw;
    float*       zp  = zout + (size_t)b * CHW + hw;
    float sum = 0.f;
#pragma unroll 4
    for (int c = 0; c < DDIM; ++c) {
        float v = row[c];
        float x = xp[(size_t)c * HWSZ];
        zp[(size_t)c * HWSZ] = v;
        float d = v - x;
        sum += d * d;
    }
#pragma unroll
    for (int o = 32; o; o >>= 1) sum += __shfl_down(sum, o, 64);
    __shared__ float ps[4];
    if ((tid & 63) == 0) ps[tid >> 6] = sum;
    __syncthreads();
    if (tid == 0) partials[blockIdx.x] = ps[0] + ps[1] + ps[2] + ps[3];
}

// ------------------------------------------------------- loss + perplexity
__global__ __launch_bounds__(256) void final_kernel(
        const float* __restrict__ partials, const unsigned int* __restrict__ counts,
        float* __restrict__ out_loss, float* __restrict__ out_perp) {
    const int tid = threadIdx.x;
    float s = partials[tid];
    float e = 0.f;
#pragma unroll
    for (int qq = 0; qq < 4; ++qq) {
        float p = (float)counts[tid * 4 + qq] * (1.f / 65536.f);
        e += p * logf(p + 1e-10f);
    }
#pragma unroll
    for (int o = 32; o; o >>= 1) {
        s += __shfl_down(s, o, 64);
        e += __shfl_down(e, o, 64);
    }
    __shared__ float ss[4], es[4];
    if ((tid & 63) == 0) { ss[tid >> 6] = s; es[tid >> 6] = e; }
    __syncthreads();
    if (tid == 0) {
        float S = ss[0] + ss[1] + ss[2] + ss[3];
        float E = es[0] + es[1] + es[2] + es[3];
        *out_loss = 0.25f * (S / (float)ZELEMS);
        *out_perp = expf(-E);
    }
}

extern "C" void kernel_launch(void* const* d_in, const int* in_sizes, int n_in,
                              void* d_out, int out_size, void* d_ws, size_t ws_size,
                              hipStream_t stream) {
    (void)in_sizes; (void)n_in; (void)out_size; (void)ws_size;
    const float* in = (const float*)d_in[0];
    const float* cb = (const float*)d_in[1];
    float* out  = (float*)d_out;
    float* zout = out;
    float* loss = out + ZELEMS;
    float* perp = out + ZELEMS + 1;
    float* idxf = out + ZELEMS + 2;

    unsigned int*       counts   = (unsigned int*)d_ws;
    float*              ww       = (float*)((char*)d_ws + 4096);
    float*              partials = (float*)((char*)d_ws + 8192);
    unsigned short*     Ws       = (unsigned short*)((char*)d_ws + 16384);
    unsigned long long* pbest    = (unsigned long long*)((char*)d_ws + 1064960);
    unsigned short*     Xs       = (unsigned short*)zout;  // scratch; overwritten later

    hipMemsetAsync(counts, 0, 4096, stream);
    conv_w      <<<32,   256, 0, stream>>>(cb, Ws, ww);
    conv_x      <<<4096, 256, 0, stream>>>(in, Xs);
    gemm_argmin <<<1024, 512, 0, stream>>>(Xs, Ws, ww, pbest);
    gather_kernel<<<256, 256, 0, stream>>>(in, cb, pbest, idxf, counts, zout, partials);
    final_kernel <<<1,   256, 0, stream>>>(partials, counts, loss, perp);
}

// Round 6
// 234.157 us; speedup vs baseline: 1.0513x; 1.0200x over previous
//
#include <hip/hip_runtime.h>
#include <math.h>

// VQ-VAE forward. inputs [16,256,64,64] f32 NCHW, codebook [1024,256] f32.
// N = 65536 points, D = 256, K = 1024.
// d_out f32: z_out [16,256,64,64] | loss | perplexity | idx [65536,1]
#define NPTS   65536
#define DDIM   256
#define KCODES 1024
#define HWSZ   4096
#define ZELEMS 16777216
#define CHW    1048576

// bf16-split GEMM, contraction 1024 = [xhi|xhi|xlo|xlo].[whi|wlo|whi|wlo].
// Fragment-ordered tiles; BK=32, 4 LDS buffers, prefetch distance 3,
// merged 2-barrier tile body (read-burst || stage -> barrier -> MFMA-burst
// -> counted vmcnt -> barrier), 4x-unrolled for immediate LDS offsets.
// X layout: [mt 256][chunk 16][rhalf 2][ms 8][lane 64][8] bf16 (64 MiB, z_out scratch)
// W layout: [ct 4][chunk 16][chalf 2][ms 8][lane 64][8] bf16 (1 MiB, ws)
// ws: counts u32[1K] @0 | ww f32[1K] @4096 | partials @8192 | Ws @16384 | pbest u64[4][64K] @1064960

typedef __attribute__((ext_vector_type(8))) short s16x8;
typedef __attribute__((ext_vector_type(4))) float f32x4;

#define AS1 __attribute__((address_space(1)))
#define AS3 __attribute__((address_space(3)))

__device__ __forceinline__ void bf16split(float x, unsigned short& h, unsigned short& l) {
    unsigned u  = __float_as_uint(x);
    unsigned hu = (u + 0x8000u) & 0xFFFF0000u;
    h = (unsigned short)(hu >> 16);
    float r = x - __uint_as_float(hu);
    l = (unsigned short)((__float_as_uint(r) + 0x8000u) >> 16);
}

// ------------------------------------------- conv_w: codebook -> tiles + ||w||^2
__global__ __launch_bounds__(256) void conv_w(const float* __restrict__ cb,
                                              unsigned short* __restrict__ Ws,
                                              float* __restrict__ ww) {
    int gid  = blockIdx.x * 256 + threadIdx.x;           // 0..8191
    int code = gid >> 3, o32 = gid & 7;
    int ct = code >> 8, r256 = code & 255, rh = r256 >> 7, rr = r256 & 127;
    unsigned short hi[32], lo[32];
    float ss = 0.f;
#pragma unroll
    for (int j4 = 0; j4 < 8; ++j4) {
        float4 v = *(const float4*)(cb + (size_t)code * DDIM + o32 * 32 + j4 * 4);
        ss += v.x * v.x + v.y * v.y + v.z * v.z + v.w * v.w;
        bf16split(v.x, hi[j4*4+0], lo[j4*4+0]);
        bf16split(v.y, hi[j4*4+1], lo[j4*4+1]);
        bf16split(v.z, hi[j4*4+2], lo[j4*4+2]);
        bf16split(v.w, hi[j4*4+3], lo[j4*4+3]);
    }
    ss += __shfl_down(ss, 4, 8);
    ss += __shfl_down(ss, 2, 8);
    ss += __shfl_down(ss, 1, 8);
    if (o32 == 0) ww[code] = ss;
    size_t bh = (size_t)ct * 131072 + (size_t)o32       * 8192 + rh * 4096 + (rr >> 4) * 512;
    size_t bl = (size_t)ct * 131072 + (size_t)(o32 + 8) * 8192 + rh * 4096 + (rr >> 4) * 512;
#pragma unroll
    for (int oct = 0; oct < 4; ++oct) {
        size_t fo = (size_t)((rr & 15) + 16 * oct) * 8;
        *(s16x8*)(Ws + bh + fo) = *(const s16x8*)&hi[oct * 8];
        *(s16x8*)(Ws + bl + fo) = *(const s16x8*)&lo[oct * 8];
    }
}

// --------------------------------- conv_x: NCHW f32 -> fragment-ordered bf16
__global__ __launch_bounds__(256) void conv_x(const float* __restrict__ in,
                                              unsigned short* __restrict__ Xs) {
    __shared__ float xt[32 * 128];                       // 16 KB
    const int tid = threadIdx.x;
    const int rg = blockIdx.x >> 3, dc = blockIdx.x & 7;
    const int mt = rg >> 1, rhalf = rg & 1;
    const int b = (rg * 128) >> 12, hw0 = (rg * 128) & 4095;
    const float* src = in + (size_t)b * CHW + (size_t)(dc * 32) * HWSZ + hw0;
#pragma unroll
    for (int r = 0; r < 16; ++r) {
        int e = r * 256 + tid, dd = e >> 7, i = e & 127;
        xt[dd * 128 + i] = src[(size_t)dd * HWSZ + i];
    }
    __syncthreads();
#pragma unroll
    for (int hl = 0; hl < 2; ++hl) {
        int g = hl * 256 + tid;
        int row = g >> 2, o = g & 3;
        unsigned short hi[8], lo[8];
#pragma unroll
        for (int j = 0; j < 8; ++j)
            bf16split(xt[(o * 8 + j) * 128 + row], hi[j], lo[j]);
        size_t fo = rhalf * 4096 + (size_t)(row >> 4) * 512 + (size_t)((row & 15) + 16 * o) * 8;
        size_t bh = (size_t)mt * 131072 + (size_t)dc       * 8192 + fo;
        size_t bl = (size_t)mt * 131072 + (size_t)(dc + 8) * 8192 + fo;
        *(s16x8*)(Xs + bh) = *(const s16x8*)hi;
        *(s16x8*)(Xs + bl) = *(const s16x8*)lo;
    }
}

// --------------------------------------- gemm_argmin: pipelined MFMA + argmin
// 1024 blocks x 512 threads (8 waves 2Mx4N; wave tile 128x64). BK=32.
// XCD swizzle: 4 nt-blocks of one mb run concurrently on one XCD (share X in L2).
__global__ __launch_bounds__(512) void gemm_argmin(
        const unsigned short* __restrict__ Xs, const unsigned short* __restrict__ Ws,
        const float* __restrict__ ww, unsigned long long* __restrict__ pbest) {
    __shared__ unsigned short lds[65536];                // 128 KB = 4 bufs x 16384 shorts
    const int tid = threadIdx.x, lane = tid & 63, w = tid >> 6;
    const int wm = w >> 2, wn = w & 3;
    const int col = lane & 15, q = lane >> 4;
    const int bid = blockIdx.x;
    const int xcd = bid & 7, slot = bid >> 3;
    const int nt = slot & 3, mb = (slot >> 2) * 8 + xcd;

    const unsigned short* XsB = Xs + (size_t)mb * 131072;
    const unsigned short* WsB = Ws + (size_t)nt * 131072;

    f32x4 acc[8][4] = {};

    const int aoff = wm * 4096 + lane * 8;               // A frag base (shorts)
    const int boff = 8192 + (wn >> 1) * 4096 + (wn & 1) * 2048 + lane * 8;

    // stage one 8 KB granule (1 instr/wave); db = dest buffer (compile-time)
    auto SA = [&](int g, int h, int db) {
        const int kA = (g & 7) | ((g >> 4) << 3);        // hi,hi,lo,lo
        const unsigned short* src = XsB + kA * 8192 + h * 4096 + tid * 8;
        __builtin_amdgcn_global_load_lds(
            (const AS1 unsigned*)src,
            (AS3 unsigned*)&lds[db * 16384 + h * 4096 + w * 512], 16, 0, 0);
    };
    auto SB = [&](int g, int h, int db) {
        const int kW = (g & 7) | (((g >> 3) & 1) << 3);  // hi,lo,hi,lo
        const unsigned short* src = WsB + kW * 8192 + h * 4096 + tid * 8;
        __builtin_amdgcn_global_load_lds(
            (const AS1 unsigned*)src,
            (AS3 unsigned*)&lds[db * 16384 + 8192 + h * 4096 + w * 512], 16, 0, 0);
    };

    // merged tile body: read-burst + stage -> barrier -> 32 MFMA -> gate -> barrier
    auto TILE = [&](int g, int u16, bool stg, int db, int gate) {
        s16x8 a[8], b[4];
        // read order: a0, b0..b3, a1..a7 -> first MFMA needs only first 5 reads
        a[0] = *(const s16x8*)&lds[u16 + aoff];
        b[0] = *(const s16x8*)&lds[u16 + boff];
        b[1] = *(const s16x8*)&lds[u16 + boff + 512];
        b[2] = *(const s16x8*)&lds[u16 + boff + 1024];
        b[3] = *(const s16x8*)&lds[u16 + boff + 1536];
#pragma unroll
        for (int mf = 1; mf < 8; ++mf)
            a[mf] = *(const s16x8*)&lds[u16 + aoff + mf * 512];
        if (stg) { SA(g + 3, 0, db); SA(g + 3, 1, db); SB(g + 3, 0, db); SB(g + 3, 1, db); }
        __builtin_amdgcn_s_barrier();
        __builtin_amdgcn_s_setprio(1);
#pragma unroll
        for (int mf = 0; mf < 8; ++mf) {
            acc[mf][0] = __builtin_amdgcn_mfma_f32_16x16x32_bf16(a[mf], b[0], acc[mf][0], 0, 0, 0);
            acc[mf][1] = __builtin_amdgcn_mfma_f32_16x16x32_bf16(a[mf], b[1], acc[mf][1], 0, 0, 0);
            acc[mf][2] = __builtin_amdgcn_mfma_f32_16x16x32_bf16(a[mf], b[2], acc[mf][2], 0, 0, 0);
            acc[mf][3] = __builtin_amdgcn_mfma_f32_16x16x32_bf16(a[mf], b[3], acc[mf][3], 0, 0, 0);
        }
        __builtin_amdgcn_s_setprio(0);
        if (gate == 8)      asm volatile("s_waitcnt vmcnt(8)" ::: "memory");
        else if (gate == 4) asm volatile("s_waitcnt vmcnt(4)" ::: "memory");
        else if (gate == 0) asm volatile("s_waitcnt vmcnt(0)" ::: "memory");
        __builtin_amdgcn_s_barrier();
    };

    // prologue: stage tiles 0,1,2; gate so tile 0 is fully resident
    SA(0, 0, 0); SA(0, 1, 0); SB(0, 0, 0); SB(0, 1, 0);
    SA(1, 0, 1); SA(1, 1, 1); SB(1, 0, 1); SB(1, 1, 1);
    SA(2, 0, 2); SA(2, 1, 2); SB(2, 0, 2); SB(2, 1, 2);
    asm volatile("s_waitcnt vmcnt(8)" ::: "memory");
    __builtin_amdgcn_s_barrier();

    for (int gq = 0; gq < 7; ++gq) {                     // tiles 0..27
        const int g0 = gq * 4;
#pragma unroll
        for (int u = 0; u < 4; ++u)
            TILE(g0 + u, u * 16384, true, (u + 3) & 3, 8);
    }
    TILE(28, 0,         true,  3, 8);                    // stages 31 -> buf 3
    TILE(29, 16384,     false, 0, 4);
    TILE(30, 2 * 16384, false, 0, 0);
    TILE(31, 3 * 16384, false, 0, -1);

    // ---- epilogue: per-row argmin -> packed u64 (monotonic dist, global k)
    __syncthreads();
    unsigned long long* kbuf = (unsigned long long*)lds;  // [256][4]
    float wv[4];
#pragma unroll
    for (int nf = 0; nf < 4; ++nf) wv[nf] = ww[nt * 256 + wn * 64 + nf * 16 + col];
#pragma unroll
    for (int mf = 0; mf < 8; ++mf)
#pragma unroll
        for (int r = 0; r < 4; ++r) {
            unsigned long long key = ~0ull;
#pragma unroll
            for (int nf = 0; nf < 4; ++nf) {
                int kg = nt * 256 + wn * 64 + nf * 16 + col;
                float sd = wv[nf] - 2.f * acc[mf][nf][r];
                unsigned u = __float_as_uint(sd);
                u = (u & 0x80000000u) ? ~u : (u | 0x80000000u);
                unsigned long long kk = ((unsigned long long)u << 32) | (unsigned)kg;
                key = kk < key ? kk : key;
            }
#pragma unroll
            for (int off = 1; off < 16; off <<= 1) {
                unsigned klo = __shfl_xor((unsigned)key, off, 64);
                unsigned khi = __shfl_xor((unsigned)(key >> 32), off, 64);
                unsigned long long ok = ((unsigned long long)khi << 32) | klo;
                key = ok < key ? ok : key;
            }
            if (col == 0) kbuf[(wm * 128 + mf * 16 + q * 4 + r) * 4 + wn] = key;
        }
    __syncthreads();
    if (tid < 256) {
        unsigned long long k0 = kbuf[tid * 4], k1 = kbuf[tid * 4 + 1];
        unsigned long long k2 = kbuf[tid * 4 + 2], k3 = kbuf[tid * 4 + 3];
        unsigned long long km = k0 < k1 ? k0 : k1;
        km = k2 < km ? k2 : km;
        km = k3 < km ? k3 : km;
        pbest[(size_t)nt * 65536 + mb * 256 + tid] = km;
    }
}

// --------------------- gather: cross-block argmin + idx + z_out + loss + counts
__global__ __launch_bounds__(256) void gather_kernel(
        const float* __restrict__ in, const float* __restrict__ cb,
        const unsigned long long* __restrict__ pbest, float* __restrict__ idx_out,
        unsigned int* __restrict__ counts, float* __restrict__ zout,
        float* __restrict__ partials) {
    const int tid = threadIdx.x;
    const int n   = blockIdx.x * 256 + tid;
    unsigned long long km = pbest[n];
#pragma unroll
    for (int nt = 1; nt < 4; ++nt) {
        unsigned long long k = pbest[(size_t)nt * 65536 + n];
        km = k < km ? k : km;
    }
    const int r = (int)(km & 0xFFFFFFFFu);
    idx_out[n] = (float)r;
    atomicAdd(&counts[r], 1u);

    const int b = n >> 12, hw = n & 4095;
    const float* row = cb + (size_t)r * DDIM;
    const float* xp  = in   + (size_t)b * CHW + hw;
    float*       zp  = zout + (size_t)b * CHW + hw;
    float sum = 0.f;
#pragma unroll 4
    for (int c = 0; c < DDIM; ++c) {
        float v = row[c];
        float x = xp[(size_t)c * HWSZ];
        zp[(size_t)c * HWSZ] = v;
        float d = v - x;
        sum += d * d;
    }
#pragma unroll
    for (int o = 32; o; o >>= 1) sum += __shfl_down(sum, o, 64);
    __shared__ float ps[4];
    if ((tid & 63) == 0) ps[tid >> 6] = sum;
    __syncthreads();
    if (tid == 0) partials[blockIdx.x] = ps[0] + ps[1] + ps[2] + ps[3];
}

// ------------------------------------------------------- loss + perplexity
__global__ __launch_bounds__(256) void final_kernel(
        const float* __restrict__ partials, const unsigned int* __restrict__ counts,
        float* __restrict__ out_loss, float* __restrict__ out_perp) {
    const int tid = threadIdx.x;
    float s = partials[tid];
    float e = 0.f;
#pragma unroll
    for (int qq = 0; qq < 4; ++qq) {
        float p = (float)counts[tid * 4 + qq] * (1.f / 65536.f);
        e += p * logf(p + 1e-10f);
    }
#pragma unroll
    for (int o = 32; o; o >>= 1) {
        s += __shfl_down(s, o, 64);
        e += __shfl_down(e, o, 64);
    }
    __shared__ float ss[4], es[4];
    if ((tid & 63) == 0) { ss[tid >> 6] = s; es[tid >> 6] = e; }
    __syncthreads();
    if (tid == 0) {
        float S = ss[0] + ss[1] + ss[2] + ss[3];
        float E = es[0] + es[1] + es[2] + es[3];
        *out_loss = 0.25f * (S / (float)ZELEMS);
        *out_perp = expf(-E);
    }
}

extern "C" void kernel_launch(void* const* d_in, const int* in_sizes, int n_in,
                              void* d_out, int out_size, void* d_ws, size_t ws_size,
                              hipStream_t stream) {
    (void)in_sizes; (void)n_in; (void)out_size; (void)ws_size;
    const float* in = (const float*)d_in[0];
    const float* cb = (const float*)d_in[1];
    float* out  = (float*)d_out;
    float* zout = out;
    float* loss = out + ZELEMS;
    float* perp = out + ZELEMS + 1;
    float* idxf = out + ZELEMS + 2;

    unsigned int*       counts   = (unsigned int*)d_ws;
    float*              ww       = (float*)((char*)d_ws + 4096);
    float*              partials = (float*)((char*)d_ws + 8192);
    unsigned short*     Ws       = (unsigned short*)((char*)d_ws + 16384);
    unsigned long long* pbest    = (unsigned long long*)((char*)d_ws + 1064960);
    unsigned short*     Xs       = (unsigned short*)zout;  // scratch; overwritten later

    hipMemsetAsync(counts, 0, 4096, stream);
    conv_w      <<<32,   256, 0, stream>>>(cb, Ws, ww);
    conv_x      <<<4096, 256, 0, stream>>>(in, Xs);
    gemm_argmin <<<1024, 512, 0, stream>>>(Xs, Ws, ww, pbest);
    gather_kernel<<<256, 256, 0, stream>>>(in, cb, pbest, idxf, counts, zout, partials);
    final_kernel <<<1,   256, 0, stream>>>(partials, counts, loss, perp);
}